// Round 12
// baseline (1183.939 us; speedup 1.0000x reference)
//
#include <hip/hip_runtime.h>

#define NXc 256
#define NTc 256
#define NBLK 64           // 2 batches x 32 nodes (8 rows each), 1024 thr/blk
#define DTv 0.0005f
#define INVD 0.2f

// ws float offsets
#define COEF_OFF 0        // 1024 floats
#define EX_OFF  1024      // byte 4096 (8B aligned): u64[2 par][64 blk][8 entry][256 col]
#define EX_BLK  2048      // u64 per block slot
// entries: e0=syy[0] e1=sxy[0] e2=sxy[1] e3=sxx[0] e4=syy[6] e5=syy[7] e6=sxy[7] e7=sxx[7]

__device__ __forceinline__ unsigned long long tld(const unsigned long long* p) {
  return __hip_atomic_load(p, __ATOMIC_RELAXED, __HIP_MEMORY_SCOPE_AGENT);
}
__device__ __forceinline__ void tst(unsigned long long* p, float v, unsigned tag) {
  unsigned long long u = ((unsigned long long)tag << 32) | (unsigned long long)__float_as_uint(v);
  __hip_atomic_store(p, u, __ATOMIC_RELAXED, __HIP_MEMORY_SCOPE_AGENT);
}
#define TVAL(x) __uint_as_float((unsigned)(x))
#define TTAG(x) ((unsigned)((x) >> 32))

__device__ __forceinline__ void bar_lds() {
  asm volatile("s_waitcnt lgkmcnt(0)" ::: "memory");
  __builtin_amdgcn_s_barrier();
  asm volatile("" ::: "memory");
}

__global__ __launch_bounds__(256) void setup_kernel(
    const float* __restrict__ lamb, const float* __restrict__ mu,
    const float* __restrict__ buoy, float* __restrict__ coef)
{
  __shared__ float red[256];
  const int tid = threadIdx.x;
  float m = 0.0f;
  for (int i = tid; i < 256*256; i += 256)
    m = fmaxf(m, sqrtf((lamb[i] + 2.0f*mu[i]) * buoy[i]));
  red[tid] = m;
  __syncthreads();
  for (int s = 128; s > 0; s >>= 1) {
    if (tid < s) red[tid] = fmaxf(red[tid], red[tid+s]);
    __syncthreads();
  }
  const float maxv = red[0];
  const float i_f = (float)tid;
  const float w = 20.0f;
  float f1 = fminf(fmaxf((w - i_f) * (1.0f/w), 0.0f), 1.0f);
  float f2 = fminf(fmaxf((i_f - (256.0f - 1.0f - w)) * (1.0f/w), 0.0f), 1.0f);
  float frac = fmaxf(f1, f2);
  float sigma_max = 3.0f * maxv * 6.907755278982137f / (2.0f * w * 5.0f);
  float sigma = sigma_max * frac * frac;
  float alpha = 3.14159265358979323f * 25.0f * (1.0f - frac);
  float bc = expf(-(sigma + alpha) * 0.0005f);
  float ac = sigma / (sigma + alpha + 1e-9f) * (bc - 1.0f);
  coef[tid]       = ac;  // ay
  coef[256 + tid] = bc;  // by
  coef[512 + tid] = ac;  // ax
  coef[768 + tid] = bc;  // bx
}

// velocity update for cell k (literal!), rr = ty+4k, V row = rr
#define VUPD(k, syA, syB, sxyC, sxyCm, sxyD, sxxC, sxxCp, upok, dnok)      \
  { float d_, t1_, t2_, t3_, t4_;                                          \
    d_ = (upok) ? ((syB) - (syA))*INVD : 0.f;                              \
    myy_[k] = vby[k]*myy_[k] + vay[k]*d_; t1_ = d_ + myy_[k];              \
    d_ = xm_ok ? ((sxyC) - (sxyCm))*INVD : 0.f;                            \
    myx_[k] = bxv*myx_[k] + axv*d_; t2_ = d_ + myx_[k];                    \
    d_ = (dnok) ? ((sxyD) - (sxyC))*INVD : 0.f;                            \
    mxyy_[k] = vby[k]*mxyy_[k] + vay[k]*d_; t3_ = d_ + mxyy_[k];           \
    d_ = xp_ok ? ((sxxCp) - (sxxC))*INVD : 0.f;                            \
    mxx_[k] = bxv*mxx_[k] + axv*d_; t4_ = d_ + mxx_[k];                    \
    vy_[k] += vdtb[k]*(t1_+t2_);                                           \
    vx_[k] += vdtb[k]*(t3_+t4_);                                           \
    if ((k) == sk0) vy_[k] += a0*vdtb[k];                                  \
    if ((k) == sk1) vy_[k] += a1*vdtb[k];                                  \
    V[0][ty + 4*(k)][tx] = vy_[k]; V[1][ty + 4*(k)][tx] = vx_[k]; }

// interior cell: S rows (r-1, r, r+1) all in LDS
#define VINT(k, r) VUPD(k, S[0][(r)-1][tx], S[0][r][tx], S[1][r][tx],      \
                        S[1][r][txm], S[1][(r)+1][tx], S[2][r][tx],        \
                        S[2][r][txp], true, true)

// stress update for cell j (literal), rs = ty+4j, V rows rs..rs+2
#define SUPD(j, rs)                                                        \
  { float d_, u5_, u6_, u7_, u8_; const int gy_ = lo + (rs);               \
    d_ = (gy_ < 255) ? (V[0][(rs)+2][tx]-V[0][(rs)+1][tx])*INVD : 0.f;     \
    mvyy_[j] = sby[j]*mvyy_[j] + say[j]*d_; u5_ = d_ + mvyy_[j];           \
    d_ = xm_ok ? (V[1][(rs)+1][tx]-V[1][(rs)+1][txm])*INVD : 0.f;          \
    mvxx_[j] = bxv*mvxx_[j] + axv*d_; u6_ = d_ + mvxx_[j];                 \
    syy_[j] += DTv*(sl2m[j]*u5_ + slam[j]*u6_);                            \
    sxx_[j] += DTv*(slam[j]*u5_ + sl2m[j]*u6_);                            \
    d_ = xm_ok ? (V[0][(rs)+1][tx]-V[0][(rs)+1][txm])*INVD : 0.f;          \
    mvyx_[j] = bxv*mvyx_[j] + axv*d_; u7_ = d_ + mvyx_[j];                 \
    d_ = (gy_ > 0) ? (V[1][(rs)+1][tx]-V[1][(rs)][tx])*INVD : 0.f;         \
    mvxy_[j] = sby[j]*mvxy_[j] + say[j]*d_; u8_ = d_ + mvxy_[j];           \
    sxy_[j] += DTv*smu[j]*(u7_+u8_);                                       \
    S[0][rs][tx]=syy_[j]; S[1][rs][tx]=sxy_[j]; S[2][rs][tx]=sxx_[j]; }

__global__ __launch_bounds__(1024) void elastic_w8(
    const float* __restrict__ lamb_g, const float* __restrict__ mu_g,
    const float* __restrict__ buoy_g, const float* __restrict__ amps,
    const int* __restrict__ src_loc, const int* __restrict__ rec_loc,
    float* __restrict__ ws, float* __restrict__ out)
{
  __shared__ float S[3][8][NXc];    // own stress rows 0..7 (gy = lo+r)
  __shared__ float V[2][10][NXc];   // v rows idx rr=0..9 (gy = lo+rr-1)

  const int blk = blockIdx.x;
  const int b = blk >> 5, n = blk & 31;
  const int tid = threadIdx.x;
  const int ty = tid >> 8, tx = tid & 255;    // ty wave-uniform (4 waves each)
  const int lo = n << 3;
  const bool hasUp = n > 0, hasDn = n < 31;
  const int txm = tx ? tx-1 : 0;
  const int txp = (tx < 255) ? tx+1 : 255;
  const bool xm_ok = tx > 0, xp_ok = tx < 255;

  const float* coef = ws + COEF_OFF;
  unsigned long long* exb = (unsigned long long*)(ws + EX_OFF);
  const float axv = coef[512+tx], bxv = coef[768+tx];

  // v-cells k=0..2: rr=ty+4k (ty>=2 has only k=0,1), gy=lo+rr-1
  float vy_[3], vx_[3], myy_[3], myx_[3], mxyy_[3], mxx_[3];
  float vay[3], vby[3], vdtb[3];
  #pragma unroll
  for (int k = 0; k < 3; ++k) {
    const int rr = ty + 4*k;
    const int gy = lo + rr - 1;
    const bool ok = (rr < 10) && (gy >= 0) && (gy < 256);
    const int gc = ok ? gy : 0;
    vdtb[k] = ok ? DTv*buoy_g[gc*NXc+tx] : 0.f;
    vay[k] = ok ? coef[gc] : 0.f;
    vby[k] = ok ? coef[256+gc] : 1.f;
    vy_[k]=vx_[k]=myy_[k]=myx_[k]=mxyy_[k]=mxx_[k]=0.f;
  }
  // s-cells j=0,1: rows ty, ty+4 (always in grid)
  float syy_[2], sxy_[2], sxx_[2], mvyy_[2], mvxx_[2], mvyx_[2], mvxy_[2];
  float slam[2], smu[2], sl2m[2], say[2], sby[2];
  #pragma unroll
  for (int j = 0; j < 2; ++j) {
    const int gy = lo + ty + 4*j;
    slam[j] = lamb_g[gy*NXc+tx]; smu[j] = mu_g[gy*NXc+tx];
    sl2m[j] = slam[j]+2.f*smu[j];
    say[j] = coef[gy]; sby[j] = coef[256+gy];
    syy_[j]=sxy_[j]=sxx_[j]=mvyy_[j]=mvxx_[j]=mvyx_[j]=mvxy_[j]=0.f;
  }

  // sources: rr = sy-lo+1 in [0,10); owner ty == rr&3, k = rr>>2
  int sk0=-1, sk1=-1, so0=0, so1=0;
  for (int i = 0; i < 4; ++i) {
    const int sb = i>>1, sy = src_loc[2*i], sx = src_loc[2*i+1];
    if (sb == b && sx == tx) {
      const int rr = sy - lo + 1;
      if (rr >= 0 && rr < 10 && (rr & 3) == ty) {
        const int k = rr >> 2;
        if (sk0 < 0) { sk0=k; so0=i*NTc; } else { sk1=k; so1=i*NTc; }
      }
    }
  }
  // receivers: this thread's two own recordable v-rows
  const int gyA = lo + ((ty==0)?3:(ty==1)?0:(ty==2)?1:2);
  const int gyB = lo + ((ty==0)?7:(ty==1)?4:(ty==2)?5:6);
  unsigned long long mA0=0,mA1=0,mB0=0,mB1=0;
  for (int i = 0; i < 128; ++i) {
    const int rb=i>>6, ry=rec_loc[2*i], rx=rec_loc[2*i+1];
    if (rb==b && rx==tx) {
      const unsigned long long bit = 1ull << (i&63);
      if (ry==gyA) { if (i<64) mA0|=bit; else mA1|=bit; }
      if (ry==gyB) { if (i<64) mB0|=bit; else mB1|=bit; }
    }
  }
  const bool recA=(mA0|mA1)!=0ull, recB=(mB0|mB1)!=0ull;

  { float* p=&S[0][0][0]; for(int i=tid;i<3*8*NXc;i+=1024) p[i]=0.f;
    float* q=&V[0][0][0]; for(int i=tid;i<2*10*NXc;i+=1024) q[i]=0.f; }
  __syncthreads();

  for (int t = 0; t < NTc; ++t) {
    float a0=0.f, a1=0.f;
    if (sk0>=0) a0=amps[so0+t];
    if (sk1>=0) a1=amps[so1+t];

    // ===== A-interior (no remote deps; overlaps the neighbor hop) =====
    if (ty==0)      { VINT(1,3) }
    else if (ty==1) { VINT(1,4) }
    else if (ty==2) { VINT(0,1) VINT(1,5) }
    else            { VINT(0,2) VINT(1,6) }

    // ===== tagged poll (only ty0/ty1 waves) =====
    unsigned long long w4=0,w5=0,w6=0,w6m=0,w7=0,w7p=0;
    unsigned long long z0=0,z1=0,z1m=0,z2=0,z3=0,z3p=0;
    if (t > 0 && ty < 2) {
      const size_t ps = (size_t)((t-1)&1)*NBLK;
      const unsigned long long* up = exb + (ps + (size_t)(hasUp?blk-1:blk))*EX_BLK;
      const unsigned long long* dn = exb + (ps + (size_t)(hasDn?blk+1:blk))*EX_BLK;
      const unsigned want = (unsigned)t;
      if (ty == 0) {
        for (;;) {
          bool ok = true;
          if (hasUp) {
            w4=tld(up+4*256+tx); w5=tld(up+5*256+tx); w6=tld(up+6*256+tx);
            w6m=tld(up+6*256+txm); w7=tld(up+7*256+tx); w7p=tld(up+7*256+txp);
            ok = ok && TTAG(w4)==want && TTAG(w5)==want && TTAG(w6)==want &&
                 TTAG(w6m)==want && TTAG(w7)==want && TTAG(w7p)==want;
          }
          if (hasDn) { z1=tld(dn+1*256+tx); ok = ok && TTAG(z1)==want; }
          if (ok) break;
        }
      } else {
        for (;;) {
          bool ok = true;
          if (hasUp) { w5=tld(up+5*256+tx); ok = ok && TTAG(w5)==want; }
          if (hasDn) {
            z0=tld(dn+0*256+tx); z1=tld(dn+1*256+tx); z1m=tld(dn+1*256+txm);
            z2=tld(dn+2*256+tx); z3=tld(dn+3*256+tx); z3p=tld(dn+3*256+txp);
            ok = ok && TTAG(z0)==want && TTAG(z1)==want && TTAG(z1m)==want &&
                 TTAG(z2)==want && TTAG(z3)==want && TTAG(z3p)==want;
          }
          if (ok) break;
        }
      }
    }
    asm volatile("" ::: "memory");

    // ===== A-boundary =====
    if (ty == 0) {
      // k0: row lo-1 (replica of up's row 7); all-remote stress inputs
      if (hasUp) {
        VUPD(0, TVAL(w4), TVAL(w5), TVAL(w6), TVAL(w6m), S[1][0][tx],
             TVAL(w7), TVAL(w7p), true, true)
      }
      // k2: row lo+7 (own bottom); only dfy term remote (down sxy[0])
      VUPD(2, S[0][6][tx], S[0][7][tx], S[1][7][tx], S[1][7][txm],
           TVAL(z1), S[2][7][tx], S[2][7][txp], true, hasDn)
    } else if (ty == 1) {
      // k0: row lo (own top); only dby term remote (up syy[7])
      VUPD(0, TVAL(w5), S[0][0][tx], S[1][0][tx], S[1][0][txm],
           S[1][1][tx], S[2][0][tx], S[2][0][txp], hasUp, true)
      // k2: row lo+8 (replica of down's row 0)
      if (hasDn) {
        VUPD(2, S[0][7][tx], TVAL(z0), TVAL(z1), TVAL(z1m), TVAL(z2),
             TVAL(z3), TVAL(z3p), true, true)
      }
    }

    // ===== recording (post-injection; async stores, don't block lgkm barrier)
    if (recA) {
      const float v = (ty==0) ? vy_[1] : vy_[0];
      unsigned long long m;
      m=mA0; while(m){int i=__ffsll((long long)m)-1;m&=m-1;out[i*NTc+t]=v;}
      m=mA1; while(m){int i=__ffsll((long long)m)-1;m&=m-1;out[(i+64)*NTc+t]=v;}
    }
    if (recB) {
      const float v = (ty==0) ? vy_[2] : vy_[1];
      unsigned long long m;
      m=mB0; while(m){int i=__ffsll((long long)m)-1;m&=m-1;out[i*NTc+t]=v;}
      m=mB1; while(m){int i=__ffsll((long long)m)-1;m&=m-1;out[(i+64)*NTc+t]=v;}
    }

    bar_lds();   // all 10 V rows visible

    // ===== B: stress rows ty, ty+4; ship boundary words ASAP =====
    unsigned long long* Q = exb + ((size_t)(t&1)*NBLK + blk)*EX_BLK + tx;
    const unsigned wt = (unsigned)(t+1);
    const bool doship = (t < NTc-1);
    SUPD(0, ty)
    if (ty == 0) {
      if (doship) { tst(Q+0*256, syy_[0], wt); tst(Q+1*256, sxy_[0], wt);
                    tst(Q+3*256, sxx_[0], wt); }
    } else if (ty == 1) {
      if (doship) { tst(Q+2*256, sxy_[0], wt); }
    }
    SUPD(1, ty+4)
    if (ty == 2) {
      if (doship) { tst(Q+4*256, syy_[1], wt); }
    } else if (ty == 3) {
      if (doship) { tst(Q+5*256, syy_[1], wt); tst(Q+6*256, sxy_[1], wt);
                    tst(Q+7*256, sxx_[1], wt); }
    }
    bar_lds();   // all 8 S rows visible for next step's A
  }
}

extern "C" void kernel_launch(void* const* d_in, const int* in_sizes, int n_in,
                              void* d_out, int out_size, void* d_ws, size_t ws_size,
                              hipStream_t stream) {
  const float* lamb    = (const float*)d_in[0];
  const float* mu      = (const float*)d_in[1];
  const float* buoy    = (const float*)d_in[2];
  const float* amps    = (const float*)d_in[3];
  const int*   src_loc = (const int*)d_in[4];
  const int*   rec_loc = (const int*)d_in[5];
  float* out = (float*)d_out;
  float* ws  = (float*)d_ws;

  // tag region must start at 0 every launch (tags 1..255 within one run)
  hipMemsetAsync((char*)ws + EX_OFF*sizeof(float), 0,
                 (size_t)2*NBLK*EX_BLK*sizeof(unsigned long long), stream);

  hipLaunchKernelGGL(setup_kernel, dim3(1), dim3(256), 0, stream,
                     lamb, mu, buoy, ws + COEF_OFF);

  void* args[] = { (void*)&lamb, (void*)&mu, (void*)&buoy, (void*)&amps,
                   (void*)&src_loc, (void*)&rec_loc, (void*)&ws, (void*)&out };
  hipLaunchCooperativeKernel((void*)elastic_w8, dim3(NBLK), dim3(1024),
                             args, 0, stream);
}

// Round 13
// 726.087 us; speedup vs baseline: 1.6306x; 1.6306x over previous
//
#include <hip/hip_runtime.h>

#define NYr 256
#define NXr 256
#define NTr 256
#define NBr 2
#define NSRCr 2
#define NRECr 64
#define NBLK 128           // 2 batches x 64 blocks, 4 rows each
#define DTv 0.0005f
#define INVD 0.2f

// workspace: coef (1024 f), then 8B-aligned tag region [2 par][128 blk][8 entry][256] u64
#define COEF_OFF 0
#define TAG_F_OFF 1024                 // byte offset 4096 (8B aligned)
#define TBLK 2048                      // u64 per block slot (8*256)
// entries: 0=syy r0, 1=sxy r0, 2=sxy r1, 3=sxx r0   (consumed by UP neighbor)
//          4=syy r2, 5=syy r3, 6=sxy r3, 7=sxx r3   (consumed by DOWN neighbor)

__device__ __forceinline__ unsigned long long tld(const unsigned long long* p) {
  return __hip_atomic_load(p, __ATOMIC_RELAXED, __HIP_MEMORY_SCOPE_AGENT);
}
__device__ __forceinline__ void tst(unsigned long long* p, float v, unsigned tag) {
  unsigned long long u = ((unsigned long long)tag << 32) | (unsigned long long)__float_as_uint(v);
  __hip_atomic_store(p, u, __ATOMIC_RELAXED, __HIP_MEMORY_SCOPE_AGENT);
}
#define TVAL(x) __uint_as_float((unsigned)(x))
#define TTAG(x) ((unsigned)((x) >> 32))

// LDS-only barrier: waits LDS ops, NOT vmem (IF stores keep flowing async).
__device__ __forceinline__ void bar_lds() {
  asm volatile("s_waitcnt lgkmcnt(0)" ::: "memory");
  __builtin_amdgcn_s_barrier();
  asm volatile("" ::: "memory");
}

__global__ __launch_bounds__(256) void setup_kernel(
    const float* __restrict__ lamb, const float* __restrict__ mu,
    const float* __restrict__ buoy, float* __restrict__ coef)
{
  __shared__ float red[256];
  const int tid = threadIdx.x;
  float m = 0.0f;
  for (int i = tid; i < NYr*NXr; i += 256)
    m = fmaxf(m, sqrtf((lamb[i] + 2.0f*mu[i]) * buoy[i]));
  red[tid] = m;
  __syncthreads();
  for (int s = 128; s > 0; s >>= 1) {
    if (tid < s) red[tid] = fmaxf(red[tid], red[tid+s]);
    __syncthreads();
  }
  const float maxv = red[0];

  const float i_f = (float)tid;
  const float w = 20.0f;
  float f1 = fminf(fmaxf((w - i_f) * (1.0f/w), 0.0f), 1.0f);
  float f2 = fminf(fmaxf((i_f - (256.0f - 1.0f - w)) * (1.0f/w), 0.0f), 1.0f);
  float frac = fmaxf(f1, f2);
  float sigma_max = 3.0f * maxv * 6.907755278982137f / (2.0f * w * 5.0f);
  float sigma = sigma_max * frac * frac;
  float alpha = 3.14159265358979323f * 25.0f * (1.0f - frac);
  float bc = expf(-(sigma + alpha) * 0.0005f);
  float ac = sigma / (sigma + alpha + 1e-9f) * (bc - 1.0f);
  coef[tid]       = ac;  // ay
  coef[256 + tid] = bc;  // by
  coef[512 + tid] = ac;  // ax
  coef[768 + tid] = bc;  // bx
}

__global__ __launch_bounds__(512) void elastic_tag4(
    const float* __restrict__ lamb_g, const float* __restrict__ mu_g,
    const float* __restrict__ buoy_g, const float* __restrict__ amps,
    const int* __restrict__ src_loc, const int* __restrict__ rec_loc,
    float* __restrict__ ws, float* __restrict__ out)
{
  __shared__ float S[3][4][NXr];   // own stress rows gy = lo..lo+3
  __shared__ float V[2][6][NXr];   // velocity rows gy = lo-1..lo+4

  const int blk = blockIdx.x;
  const int b = blk >> 6, bi = blk & 63;
  const int tid = threadIdx.x;
  const int ty = tid >> 8, tx = tid & 255;   // ty is wave-uniform
  const int lo = bi << 2;
  const bool hasUp = bi > 0, hasDn = bi < 63;

  const float* coef = ws + COEF_OFF;
  unsigned long long* tagb = (unsigned long long*)(ws + TAG_F_OFF);

  const int txm = tx ? tx-1 : 0;
  const int txp = (tx < 255) ? tx+1 : 255;
  const bool xm_ok = tx > 0, xp_ok = tx < 255;
  const float axv = coef[512+tx], bxv = coef[768+tx];

  // ---- velocity cells k=0..2: gy = lo-1+ty+2k ----
  float vy_[3], vx_[3], myy[3], myx[3], mxyy[3], mxx[3];
  float dtb_[3], ayv[3], byv[3];
  #pragma unroll
  for (int k = 0; k < 3; ++k) {
    const int gy = lo - 1 + ty + 2*k;
    const bool ok = (gy >= 0) && (gy < NYr);
    const int gyc = ok ? gy : 0;
    dtb_[k] = ok ? DTv * buoy_g[gyc*NXr + tx] : 0.f;
    ayv[k]  = ok ? coef[gyc] : 0.f;
    byv[k]  = ok ? coef[256 + gyc] : 1.f;
    vy_[k] = vx_[k] = myy[k] = myx[k] = mxyy[k] = mxx[k] = 0.f;
  }
  // ---- stress cells j=0,1: gy = lo+ty+2j (always in-grid) ----
  float syy_[2], sxy_[2], sxx_[2], mvyy[2], mvxx[2], mvyx[2], mvxy[2];
  float lamv[2], muv[2], l2mv[2], ays[2], bys[2];
  #pragma unroll
  for (int j = 0; j < 2; ++j) {
    const int gy = lo + ty + 2*j;
    lamv[j] = lamb_g[gy*NXr + tx]; muv[j] = mu_g[gy*NXr + tx];
    l2mv[j] = lamv[j] + 2.f*muv[j];
    ays[j] = coef[gy]; bys[j] = coef[256 + gy];
    syy_[j] = sxy_[j] = sxx_[j] = 0.f;
    mvyy[j] = mvxx[j] = mvyx[j] = mvxy[j] = 0.f;
  }

  // ---- sources (halo replicas inject too, consistently) ----
  int sk0 = -1, sk1 = -1; int so0 = 0, so1 = 0;
  for (int i = 0; i < NBr*NSRCr; ++i) {
    const int sb = i >> 1, sy = src_loc[2*i], sx = src_loc[2*i+1];
    if (sb == b && sx == tx) {
      #pragma unroll
      for (int k = 0; k < 3; ++k) {
        const int gy = lo - 1 + ty + 2*k;
        if (gy == sy) { if (sk0 < 0) { sk0 = k; so0 = i*NTr; } else { sk1 = k; so1 = i*NTr; } }
      }
    }
  }
  // ---- receivers: own cells only ----
  const int gyA = ty ? lo     : lo + 1;
  const int gyB = ty ? lo + 2 : lo + 3;
  unsigned long long mA0=0, mA1=0, mB0=0, mB1=0;
  for (int i = 0; i < NBr*NRECr; ++i) {
    const int rb = i >> 6, ry = rec_loc[2*i], rx = rec_loc[2*i+1];
    if (rb == b && rx == tx) {
      if (ry == gyA) { if (i < 64) mA0 |= 1ull<<i; else mA1 |= 1ull<<(i-64); }
      if (ry == gyB) { if (i < 64) mB0 |= 1ull<<i; else mB1 |= 1ull<<(i-64); }
    }
  }
  const bool recA = (mA0|mA1) != 0ull, recB = (mB0|mB1) != 0ull;

  // ---- zero LDS ----
  { float* p = &S[0][0][0]; for (int i = tid; i < 3*4*NXr; i += 512) p[i] = 0.f;
    float* q = &V[0][0][0]; for (int i = tid; i < 2*6*NXr; i += 512) q[i] = 0.f; }
  __syncthreads();

  for (int t = 0; t < NTr; ++t) {
    // amps prefetch (issued early)
    float a0 = 0.f, a1 = 0.f;
    if (sk0 >= 0) a0 = amps[so0 + t];
    if (sk1 >= 0) a1 = amps[so1 + t];

    // ========== issue FIRST tagged-load round BEFORE A-interior ==========
    unsigned long long u4w=0, u5w=0, u6w=0, u6mw=0, u7w=0, u7pw=0;
    unsigned long long d0w=0, d1w=0, d1mw=0, d2w=0, d3w=0, d3pw=0;
    const size_t pslot = (size_t)((t-1)&1)*NBLK;
    const unsigned long long* up = tagb + (pslot + (hasUp ? blk-1 : blk))*TBLK;
    const unsigned long long* dn = tagb + (pslot + (hasDn ? blk+1 : blk))*TBLK;
    if (t > 0) {
      if (ty == 0) {
        u4w = tld(up+4*256+tx); u5w = tld(up+5*256+tx); u6w = tld(up+6*256+tx);
        u6mw = tld(up+6*256+txm); u7w = tld(up+7*256+tx); u7pw = tld(up+7*256+txp);
        d1w = tld(dn+1*256+tx);
      } else {
        u5w = tld(up+5*256+tx);
        d0w = tld(dn+0*256+tx); d1w = tld(dn+1*256+tx); d1mw = tld(dn+1*256+txm);
        d2w = tld(dn+2*256+tx); d3w = tld(dn+3*256+tx); d3pw = tld(dn+3*256+txp);
      }
    }

    // ========== A-interior: k=1, gy = lo+1+ty (overlaps the load round) ==========
    {
      const int sr = 1 + ty;
      float d, u1, u2, u3, u4;
      d = (S[0][sr][tx] - S[0][sr-1][tx]) * INVD;
      myy[1] = byv[1]*myy[1] + ayv[1]*d; u1 = d + myy[1];
      d = xm_ok ? (S[1][sr][tx] - S[1][sr][txm]) * INVD : 0.f;
      myx[1] = bxv*myx[1] + axv*d; u2 = d + myx[1];
      vy_[1] += dtb_[1]*(u1+u2);
      d = (S[1][sr+1][tx] - S[1][sr][tx]) * INVD;
      mxyy[1] = byv[1]*mxyy[1] + ayv[1]*d; u3 = d + mxyy[1];
      d = xp_ok ? (S[2][sr][txp] - S[2][sr][tx]) * INVD : 0.f;
      mxx[1] = bxv*mxx[1] + axv*d; u4 = d + mxx[1];
      vx_[1] += dtb_[1]*(u3+u4);
      if (sk0 == 1) vy_[1] += a0*dtb_[1];
      if (sk1 == 1) vy_[1] += a1*dtb_[1];
      V[0][ty+2][tx] = vy_[1];
      V[1][ty+2][tx] = vx_[1];
    }

    // ========== check tags; re-poll only on miss ==========
    if (t > 0) {
      const unsigned want = (unsigned)t;
      if (ty == 0) {
        for (;;) {
          const bool okU = !hasUp || (TTAG(u4w)==want && TTAG(u5w)==want && TTAG(u6w)==want &&
                                      TTAG(u6mw)==want && TTAG(u7w)==want && TTAG(u7pw)==want);
          const bool okD = !hasDn || (TTAG(d1w)==want);
          if (okU && okD) break;
          u4w = tld(up+4*256+tx); u5w = tld(up+5*256+tx); u6w = tld(up+6*256+tx);
          u6mw = tld(up+6*256+txm); u7w = tld(up+7*256+tx); u7pw = tld(up+7*256+txp);
          d1w = tld(dn+1*256+tx);
        }
      } else {
        for (;;) {
          const bool okU = !hasUp || (TTAG(u5w)==want);
          const bool okD = !hasDn || (TTAG(d0w)==want && TTAG(d1w)==want && TTAG(d1mw)==want &&
                                      TTAG(d2w)==want && TTAG(d3w)==want && TTAG(d3pw)==want);
          if (okU && okD) break;
          u5w = tld(up+5*256+tx);
          d0w = tld(dn+0*256+tx); d1w = tld(dn+1*256+tx); d1mw = tld(dn+1*256+txm);
          d2w = tld(dn+2*256+tx); d3w = tld(dn+3*256+tx); d3pw = tld(dn+3*256+txp);
        }
      }
    }

    // ========== A-boundary ==========
    if (ty == 0) {
      // k=0: gy = lo-1 (halo replica; valid iff hasUp)
      if (hasUp) {
        const float syy2 = TVAL(u4w), syy3 = TVAL(u5w);
        const float sxy3t = TVAL(u6w), sxy3m = TVAL(u6mw);
        const float sxx3t = TVAL(u7w), sxx3p = TVAL(u7pw);
        float d, u1, u2, u3, u4;
        d = (syy3 - syy2) * INVD;
        myy[0] = byv[0]*myy[0] + ayv[0]*d; u1 = d + myy[0];
        d = xm_ok ? (sxy3t - sxy3m) * INVD : 0.f;
        myx[0] = bxv*myx[0] + axv*d; u2 = d + myx[0];
        vy_[0] += dtb_[0]*(u1+u2);
        d = (S[1][0][tx] - sxy3t) * INVD;
        mxyy[0] = byv[0]*mxyy[0] + ayv[0]*d; u3 = d + mxyy[0];
        d = xp_ok ? (sxx3p - sxx3t) * INVD : 0.f;
        mxx[0] = bxv*mxx[0] + axv*d; u4 = d + mxx[0];
        vx_[0] += dtb_[0]*(u3+u4);
        if (sk0 == 0) vy_[0] += a0*dtb_[0];
        if (sk1 == 0) vy_[0] += a1*dtb_[0];
        V[0][0][tx] = vy_[0]; V[1][0][tx] = vx_[0];
      }
      // k=2: gy = lo+3 (own bottom row)
      {
        const float sxy4t = TVAL(d1w);
        float d, u1, u2, u3, u4;
        d = (S[0][3][tx] - S[0][2][tx]) * INVD;
        myy[2] = byv[2]*myy[2] + ayv[2]*d; u1 = d + myy[2];
        d = xm_ok ? (S[1][3][tx] - S[1][3][txm]) * INVD : 0.f;
        myx[2] = bxv*myx[2] + axv*d; u2 = d + myx[2];
        vy_[2] += dtb_[2]*(u1+u2);
        d = hasDn ? (sxy4t - S[1][3][tx]) * INVD : 0.f;
        mxyy[2] = byv[2]*mxyy[2] + ayv[2]*d; u3 = d + mxyy[2];
        d = xp_ok ? (S[2][3][txp] - S[2][3][tx]) * INVD : 0.f;
        mxx[2] = bxv*mxx[2] + axv*d; u4 = d + mxx[2];
        vx_[2] += dtb_[2]*(u3+u4);
        if (sk0 == 2) vy_[2] += a0*dtb_[2];
        if (sk1 == 2) vy_[2] += a1*dtb_[2];
        V[0][4][tx] = vy_[2]; V[1][4][tx] = vx_[2];
      }
    } else {
      // k=0: gy = lo (own top row)
      {
        const float syyU = TVAL(u5w);
        float d, u1, u2, u3, u4;
        d = hasUp ? (S[0][0][tx] - syyU) * INVD : 0.f;
        myy[0] = byv[0]*myy[0] + ayv[0]*d; u1 = d + myy[0];
        d = xm_ok ? (S[1][0][tx] - S[1][0][txm]) * INVD : 0.f;
        myx[0] = bxv*myx[0] + axv*d; u2 = d + myx[0];
        vy_[0] += dtb_[0]*(u1+u2);
        d = (S[1][1][tx] - S[1][0][tx]) * INVD;
        mxyy[0] = byv[0]*mxyy[0] + ayv[0]*d; u3 = d + mxyy[0];
        d = xp_ok ? (S[2][0][txp] - S[2][0][tx]) * INVD : 0.f;
        mxx[0] = bxv*mxx[0] + axv*d; u4 = d + mxx[0];
        vx_[0] += dtb_[0]*(u3+u4);
        if (sk0 == 0) vy_[0] += a0*dtb_[0];
        if (sk1 == 0) vy_[0] += a1*dtb_[0];
        V[0][1][tx] = vy_[0]; V[1][1][tx] = vx_[0];
      }
      // k=2: gy = lo+4 (halo replica; valid iff hasDn)
      if (hasDn) {
        const float syyD0 = TVAL(d0w), sxyD0t = TVAL(d1w), sxyD0m = TVAL(d1mw);
        const float sxyD1t = TVAL(d2w), sxxD0t = TVAL(d3w), sxxD0p = TVAL(d3pw);
        float d, u1, u2, u3, u4;
        d = (syyD0 - S[0][3][tx]) * INVD;
        myy[2] = byv[2]*myy[2] + ayv[2]*d; u1 = d + myy[2];
        d = xm_ok ? (sxyD0t - sxyD0m) * INVD : 0.f;
        myx[2] = bxv*myx[2] + axv*d; u2 = d + myx[2];
        vy_[2] += dtb_[2]*(u1+u2);
        d = (sxyD1t - sxyD0t) * INVD;
        mxyy[2] = byv[2]*mxyy[2] + ayv[2]*d; u3 = d + mxyy[2];
        d = xp_ok ? (sxxD0p - sxxD0t) * INVD : 0.f;
        mxx[2] = bxv*mxx[2] + axv*d; u4 = d + mxx[2];
        vx_[2] += dtb_[2]*(u3+u4);
        if (sk0 == 2) vy_[2] += a0*dtb_[2];
        if (sk1 == 2) vy_[2] += a1*dtb_[2];
        V[0][5][tx] = vy_[2]; V[1][5][tx] = vx_[2];
      }
    }

    bar_lds();   // all V rows visible (LDS-only wait; IF stores keep flowing)

    // ========== B: split/reordered — ship ALL 8 boundary words EARLY ==========
    unsigned long long* my = tagb + ((size_t)(t&1)*NBLK + blk)*TBLK;
    const unsigned wtag = (unsigned)(t + 1);
    if (ty == 0) {
      // ---- j0: row lo (vr=1), FULL; ship e0,e1,e3 immediately ----
      {
        float d, u5, u6, u7, u8;
        d = (V[0][2][tx] - V[0][1][tx]) * INVD;                 // dfy vy (gy=lo<=252)
        mvyy[0] = bys[0]*mvyy[0] + ays[0]*d; u5 = d + mvyy[0];
        d = xm_ok ? (V[1][1][tx] - V[1][1][txm]) * INVD : 0.f;  // dbx vx
        mvxx[0] = bxv*mvxx[0] + axv*d; u6 = d + mvxx[0];
        syy_[0] += DTv*(l2mv[0]*u5 + lamv[0]*u6);
        sxx_[0] += DTv*(lamv[0]*u5 + l2mv[0]*u6);
        d = xm_ok ? (V[0][1][tx] - V[0][1][txm]) * INVD : 0.f;  // dbx vy
        mvyx[0] = bxv*mvyx[0] + axv*d; u7 = d + mvyx[0];
        d = hasUp ? (V[1][1][tx] - V[1][0][tx]) * INVD : 0.f;   // dby vx (gy=0 iff bi=0)
        mvxy[0] = bys[0]*mvxy[0] + ays[0]*d; u8 = d + mvxy[0];
        sxy_[0] += DTv*muv[0]*(u7+u8);
        tst(my + 0*256 + tx, syy_[0], wtag);
        tst(my + 1*256 + tx, sxy_[0], wtag);
        tst(my + 3*256 + tx, sxx_[0], wtag);
        S[0][0][tx]=syy_[0]; S[1][0][tx]=sxy_[0]; S[2][0][tx]=sxx_[0];
      }
      // ---- j1: row lo+2 (vr=3): syy/sxx FIRST -> ship e4, sxy after ----
      {
        float d, u5, u6;
        d = (V[0][4][tx] - V[0][3][tx]) * INVD;                 // dfy vy (gy=lo+2<=254)
        mvyy[1] = bys[1]*mvyy[1] + ays[1]*d; u5 = d + mvyy[1];
        d = xm_ok ? (V[1][3][tx] - V[1][3][txm]) * INVD : 0.f;  // dbx vx
        mvxx[1] = bxv*mvxx[1] + axv*d; u6 = d + mvxx[1];
        syy_[1] += DTv*(l2mv[1]*u5 + lamv[1]*u6);
        sxx_[1] += DTv*(lamv[1]*u5 + l2mv[1]*u6);
        tst(my + 4*256 + tx, syy_[1], wtag);
        float u7, u8;
        d = xm_ok ? (V[0][3][tx] - V[0][3][txm]) * INVD : 0.f;  // dbx vy
        mvyx[1] = bxv*mvyx[1] + axv*d; u7 = d + mvyx[1];
        d = (V[1][3][tx] - V[1][2][tx]) * INVD;                 // dby vx (gy>=2)
        mvxy[1] = bys[1]*mvxy[1] + ays[1]*d; u8 = d + mvxy[1];
        sxy_[1] += DTv*muv[1]*(u7+u8);
        S[0][2][tx]=syy_[1]; S[1][2][tx]=sxy_[1]; S[2][2][tx]=sxx_[1];
      }
    } else {
      // ---- j1: row lo+3 (vr=4), FULL FIRST; ship e5,e6,e7 immediately ----
      {
        float d, u5, u6, u7, u8;
        d = hasDn ? (V[0][5][tx] - V[0][4][tx]) * INVD : 0.f;   // dfy vy (gy=255 iff bi=63)
        mvyy[1] = bys[1]*mvyy[1] + ays[1]*d; u5 = d + mvyy[1];
        d = xm_ok ? (V[1][4][tx] - V[1][4][txm]) * INVD : 0.f;  // dbx vx
        mvxx[1] = bxv*mvxx[1] + axv*d; u6 = d + mvxx[1];
        syy_[1] += DTv*(l2mv[1]*u5 + lamv[1]*u6);
        sxx_[1] += DTv*(lamv[1]*u5 + l2mv[1]*u6);
        d = xm_ok ? (V[0][4][tx] - V[0][4][txm]) * INVD : 0.f;  // dbx vy
        mvyx[1] = bxv*mvyx[1] + axv*d; u7 = d + mvyx[1];
        d = (V[1][4][tx] - V[1][3][tx]) * INVD;                 // dby vx (gy>=3)
        mvxy[1] = bys[1]*mvxy[1] + ays[1]*d; u8 = d + mvxy[1];
        sxy_[1] += DTv*muv[1]*(u7+u8);
        tst(my + 5*256 + tx, syy_[1], wtag);
        tst(my + 6*256 + tx, sxy_[1], wtag);
        tst(my + 7*256 + tx, sxx_[1], wtag);
        S[0][3][tx]=syy_[1]; S[1][3][tx]=sxy_[1]; S[2][3][tx]=sxx_[1];
      }
      // ---- j0: row lo+1 (vr=2): sxy FIRST -> ship e2, syy/sxx after ----
      {
        float d, u7, u8;
        d = xm_ok ? (V[0][2][tx] - V[0][2][txm]) * INVD : 0.f;  // dbx vy
        mvyx[0] = bxv*mvyx[0] + axv*d; u7 = d + mvyx[0];
        d = (V[1][2][tx] - V[1][1][tx]) * INVD;                 // dby vx (gy>=1)
        mvxy[0] = bys[0]*mvxy[0] + ays[0]*d; u8 = d + mvxy[0];
        sxy_[0] += DTv*muv[0]*(u7+u8);
        tst(my + 2*256 + tx, sxy_[0], wtag);
        float u5, u6;
        d = (V[0][3][tx] - V[0][2][tx]) * INVD;                 // dfy vy (gy<=253)
        mvyy[0] = bys[0]*mvyy[0] + ays[0]*d; u5 = d + mvyy[0];
        d = xm_ok ? (V[1][2][tx] - V[1][2][txm]) * INVD : 0.f;  // dbx vx
        mvxx[0] = bxv*mvxx[0] + axv*d; u6 = d + mvxx[0];
        syy_[0] += DTv*(l2mv[0]*u5 + lamv[0]*u6);
        sxx_[0] += DTv*(lamv[0]*u5 + l2mv[0]*u6);
        S[0][1][tx]=syy_[0]; S[1][1][tx]=sxy_[0]; S[2][1][tx]=sxx_[0];
      }
    }
    bar_lds();   // S rows visible for next step's A-interior (no vmem drain)

    // ========== recording AFTER the barrier (off the critical path) ==========
    if (recA) {
      const float v = ty ? vy_[0] : vy_[1];
      unsigned long long m = mA0; while (m) { int i = __ffsll((long long)m)-1; m &= m-1; out[i*NTr + t] = v; }
      m = mA1; while (m) { int i = __ffsll((long long)m)-1; m &= m-1; out[(i+64)*NTr + t] = v; }
    }
    if (recB) {
      const float v = ty ? vy_[1] : vy_[2];
      unsigned long long m = mB0; while (m) { int i = __ffsll((long long)m)-1; m &= m-1; out[i*NTr + t] = v; }
      m = mB1; while (m) { int i = __ffsll((long long)m)-1; m &= m-1; out[(i+64)*NTr + t] = v; }
    }
  }
}

extern "C" void kernel_launch(void* const* d_in, const int* in_sizes, int n_in,
                              void* d_out, int out_size, void* d_ws, size_t ws_size,
                              hipStream_t stream) {
  const float* lamb    = (const float*)d_in[0];
  const float* mu      = (const float*)d_in[1];
  const float* buoy    = (const float*)d_in[2];
  const float* amps    = (const float*)d_in[3];
  const int*   src_loc = (const int*)d_in[4];
  const int*   rec_loc = (const int*)d_in[5];
  float* out = (float*)d_out;
  float* ws  = (float*)d_ws;

  // tag region must start at 0 every launch (tags 1..256 within one run)
  hipMemsetAsync((char*)ws + TAG_F_OFF*sizeof(float), 0,
                 (size_t)2*NBLK*TBLK*sizeof(unsigned long long), stream);

  hipLaunchKernelGGL(setup_kernel, dim3(1), dim3(256), 0, stream,
                     lamb, mu, buoy, ws + COEF_OFF);

  void* args[] = { (void*)&lamb, (void*)&mu, (void*)&buoy, (void*)&amps,
                   (void*)&src_loc, (void*)&rec_loc, (void*)&ws, (void*)&out };
  hipLaunchCooperativeKernel((void*)elastic_tag4, dim3(NBLK), dim3(512),
                             args, 0, stream);
}

// Round 14
// 665.234 us; speedup vs baseline: 1.7797x; 1.0915x over previous
//
#include <hip/hip_runtime.h>

#define NYr 256
#define NXr 256
#define NTr 256
#define NBr 2
#define NSRCr 2
#define NRECr 64
#define NBLK 128           // 2 batches x 64 blocks, 4 rows each
#define DTv 0.0005f
#define INVD 0.2f

// workspace: coef (1024 f), then 8B-aligned tag region [2 par][128 blk][8 entry][256] u64
#define COEF_OFF 0
#define TAG_F_OFF 1024                 // byte offset 4096 (8B aligned)
#define TBLK 2048                      // u64 per block slot (8*256)
// entries: 0=syy r0, 1=sxy r0, 2=sxy r1, 3=sxx r0   (consumed by UP neighbor)
//          4=syy r2, 5=syy r3, 6=sxy r3, 7=sxx r3   (consumed by DOWN neighbor)

__device__ __forceinline__ unsigned long long tld(const unsigned long long* p) {
  return __hip_atomic_load(p, __ATOMIC_RELAXED, __HIP_MEMORY_SCOPE_AGENT);
}
__device__ __forceinline__ void tst(unsigned long long* p, float v, unsigned tag) {
  unsigned long long u = ((unsigned long long)tag << 32) | (unsigned long long)__float_as_uint(v);
  __hip_atomic_store(p, u, __ATOMIC_RELAXED, __HIP_MEMORY_SCOPE_AGENT);
}
#define TVAL(x) __uint_as_float((unsigned)(x))
#define TTAG(x) ((unsigned)((x) >> 32))

// LDS-only barrier: waits LDS ops, NOT vmem (IF stores keep flowing async).
__device__ __forceinline__ void bar_lds() {
  asm volatile("s_waitcnt lgkmcnt(0)" ::: "memory");
  __builtin_amdgcn_s_barrier();
  asm volatile("" ::: "memory");
}

__global__ __launch_bounds__(256) void setup_kernel(
    const float* __restrict__ lamb, const float* __restrict__ mu,
    const float* __restrict__ buoy, float* __restrict__ coef)
{
  __shared__ float red[256];
  const int tid = threadIdx.x;
  float m = 0.0f;
  for (int i = tid; i < NYr*NXr; i += 256)
    m = fmaxf(m, sqrtf((lamb[i] + 2.0f*mu[i]) * buoy[i]));
  red[tid] = m;
  __syncthreads();
  for (int s = 128; s > 0; s >>= 1) {
    if (tid < s) red[tid] = fmaxf(red[tid], red[tid+s]);
    __syncthreads();
  }
  const float maxv = red[0];

  const float i_f = (float)tid;
  const float w = 20.0f;
  float f1 = fminf(fmaxf((w - i_f) * (1.0f/w), 0.0f), 1.0f);
  float f2 = fminf(fmaxf((i_f - (256.0f - 1.0f - w)) * (1.0f/w), 0.0f), 1.0f);
  float frac = fmaxf(f1, f2);
  float sigma_max = 3.0f * maxv * 6.907755278982137f / (2.0f * w * 5.0f);
  float sigma = sigma_max * frac * frac;
  float alpha = 3.14159265358979323f * 25.0f * (1.0f - frac);
  float bc = expf(-(sigma + alpha) * 0.0005f);
  float ac = sigma / (sigma + alpha + 1e-9f) * (bc - 1.0f);
  coef[tid]       = ac;  // ay
  coef[256 + tid] = bc;  // by
  coef[512 + tid] = ac;  // ax
  coef[768 + tid] = bc;  // bx
}

__global__ __launch_bounds__(512) void elastic_tag5(
    const float* __restrict__ lamb_g, const float* __restrict__ mu_g,
    const float* __restrict__ buoy_g, const float* __restrict__ amps,
    const int* __restrict__ src_loc, const int* __restrict__ rec_loc,
    float* __restrict__ ws, float* __restrict__ out)
{
  __shared__ float S[3][4][NXr];   // own stress rows gy = lo..lo+3
  __shared__ float V[2][6][NXr];   // velocity rows gy = lo-1..lo+4

  const int blk = blockIdx.x;
  const int b = blk >> 6, bi = blk & 63;
  const int tid = threadIdx.x;
  const int ty = tid >> 8, tx = tid & 255;   // ty is wave-uniform
  const int lo = bi << 2;
  const bool hasUp = bi > 0, hasDn = bi < 63;

  const float* coef = ws + COEF_OFF;
  unsigned long long* tagb = (unsigned long long*)(ws + TAG_F_OFF);

  const int txm = tx ? tx-1 : 0;
  const int txp = (tx < 255) ? tx+1 : 255;
  const bool xm_ok = tx > 0, xp_ok = tx < 255;
  const float axv = coef[512+tx], bxv = coef[768+tx];

  // ---- velocity cells k=0..2: gy = lo-1+ty+2k ----
  float vy_[3], vx_[3], myy[3], myx[3], mxyy[3], mxx[3];
  float dtb_[3], ayv[3], byv[3];
  #pragma unroll
  for (int k = 0; k < 3; ++k) {
    const int gy = lo - 1 + ty + 2*k;
    const bool ok = (gy >= 0) && (gy < NYr);
    const int gyc = ok ? gy : 0;
    dtb_[k] = ok ? DTv * buoy_g[gyc*NXr + tx] : 0.f;
    ayv[k]  = ok ? coef[gyc] : 0.f;
    byv[k]  = ok ? coef[256 + gyc] : 1.f;
    vy_[k] = vx_[k] = myy[k] = myx[k] = mxyy[k] = mxx[k] = 0.f;
  }
  // ---- stress cells j=0,1: gy = lo+ty+2j (always in-grid) ----
  float syy_[2], sxy_[2], sxx_[2], mvyy[2], mvxx[2], mvyx[2], mvxy[2];
  float lamv[2], muv[2], l2mv[2], ays[2], bys[2];
  #pragma unroll
  for (int j = 0; j < 2; ++j) {
    const int gy = lo + ty + 2*j;
    lamv[j] = lamb_g[gy*NXr + tx]; muv[j] = mu_g[gy*NXr + tx];
    l2mv[j] = lamv[j] + 2.f*muv[j];
    ays[j] = coef[gy]; bys[j] = coef[256 + gy];
    syy_[j] = sxy_[j] = sxx_[j] = 0.f;
    mvyy[j] = mvxx[j] = mvyx[j] = mvxy[j] = 0.f;
  }

  // ---- sources (halo replicas inject too, consistently) ----
  int sk0 = -1, sk1 = -1; int so0 = 0, so1 = 0;
  for (int i = 0; i < NBr*NSRCr; ++i) {
    const int sb = i >> 1, sy = src_loc[2*i], sx = src_loc[2*i+1];
    if (sb == b && sx == tx) {
      #pragma unroll
      for (int k = 0; k < 3; ++k) {
        const int gy = lo - 1 + ty + 2*k;
        if (gy == sy) { if (sk0 < 0) { sk0 = k; so0 = i*NTr; } else { sk1 = k; so1 = i*NTr; } }
      }
    }
  }
  // ---- receivers: own cells only ----
  const int gyA = ty ? lo     : lo + 1;
  const int gyB = ty ? lo + 2 : lo + 3;
  unsigned long long mA0=0, mA1=0, mB0=0, mB1=0;
  for (int i = 0; i < NBr*NRECr; ++i) {
    const int rb = i >> 6, ry = rec_loc[2*i], rx = rec_loc[2*i+1];
    if (rb == b && rx == tx) {
      if (ry == gyA) { if (i < 64) mA0 |= 1ull<<i; else mA1 |= 1ull<<(i-64); }
      if (ry == gyB) { if (i < 64) mB0 |= 1ull<<i; else mB1 |= 1ull<<(i-64); }
    }
  }
  const bool recA = (mA0|mA1) != 0ull, recB = (mB0|mB1) != 0ull;

  // ---- zero LDS ----
  { float* p = &S[0][0][0]; for (int i = tid; i < 3*4*NXr; i += 512) p[i] = 0.f;
    float* q = &V[0][0][0]; for (int i = tid; i < 2*6*NXr; i += 512) q[i] = 0.f; }
  __syncthreads();

  for (int t = 0; t < NTr; ++t) {
    // amps prefetch (issued early)
    float a0 = 0.f, a1 = 0.f;
    if (sk0 >= 0) a0 = amps[so0 + t];
    if (sk1 >= 0) a1 = amps[so1 + t];

    // ========== issue FIRST tagged-load round BEFORE A-interior ==========
    unsigned long long u4w=0, u5w=0, u6w=0, u6mw=0, u7w=0, u7pw=0;
    unsigned long long d0w=0, d1w=0, d1mw=0, d2w=0, d3w=0, d3pw=0;
    const size_t pslot = (size_t)((t-1)&1)*NBLK;
    const unsigned long long* up = tagb + (pslot + (hasUp ? blk-1 : blk))*TBLK;
    const unsigned long long* dn = tagb + (pslot + (hasDn ? blk+1 : blk))*TBLK;
    if (t > 0) {
      if (ty == 0) {
        u4w = tld(up+4*256+tx); u5w = tld(up+5*256+tx); u6w = tld(up+6*256+tx);
        u6mw = tld(up+6*256+txm); u7w = tld(up+7*256+tx); u7pw = tld(up+7*256+txp);
        d1w = tld(dn+1*256+tx);
      } else {
        u5w = tld(up+5*256+tx);
        d0w = tld(dn+0*256+tx); d1w = tld(dn+1*256+tx); d1mw = tld(dn+1*256+txm);
        d2w = tld(dn+2*256+tx); d3w = tld(dn+3*256+tx); d3pw = tld(dn+3*256+txp);
      }
    }

    // ========== A-interior: k=1, gy = lo+1+ty (overlaps the load round) ==========
    {
      const int sr = 1 + ty;
      float d, u1, u2, u3, u4;
      d = (S[0][sr][tx] - S[0][sr-1][tx]) * INVD;
      myy[1] = byv[1]*myy[1] + ayv[1]*d; u1 = d + myy[1];
      d = xm_ok ? (S[1][sr][tx] - S[1][sr][txm]) * INVD : 0.f;
      myx[1] = bxv*myx[1] + axv*d; u2 = d + myx[1];
      vy_[1] += dtb_[1]*(u1+u2);
      d = (S[1][sr+1][tx] - S[1][sr][tx]) * INVD;
      mxyy[1] = byv[1]*mxyy[1] + ayv[1]*d; u3 = d + mxyy[1];
      d = xp_ok ? (S[2][sr][txp] - S[2][sr][tx]) * INVD : 0.f;
      mxx[1] = bxv*mxx[1] + axv*d; u4 = d + mxx[1];
      vx_[1] += dtb_[1]*(u3+u4);
      if (sk0 == 1) vy_[1] += a0*dtb_[1];
      if (sk1 == 1) vy_[1] += a1*dtb_[1];
      V[0][ty+2][tx] = vy_[1];
      V[1][ty+2][tx] = vx_[1];
    }

    // ========== check tags; on miss back off (s_sleep) then re-poll ==========
    if (t > 0) {
      const unsigned want = (unsigned)t;
      if (ty == 0) {
        for (;;) {
          const bool okU = !hasUp || (TTAG(u4w)==want && TTAG(u5w)==want && TTAG(u6w)==want &&
                                      TTAG(u6mw)==want && TTAG(u7w)==want && TTAG(u7pw)==want);
          const bool okD = !hasDn || (TTAG(d1w)==want);
          if (okU && okD) break;
          __builtin_amdgcn_s_sleep(1);     // ~64 cyc backoff: cut MALL poll contention
          u4w = tld(up+4*256+tx); u5w = tld(up+5*256+tx); u6w = tld(up+6*256+tx);
          u6mw = tld(up+6*256+txm); u7w = tld(up+7*256+tx); u7pw = tld(up+7*256+txp);
          d1w = tld(dn+1*256+tx);
        }
      } else {
        for (;;) {
          const bool okU = !hasUp || (TTAG(u5w)==want);
          const bool okD = !hasDn || (TTAG(d0w)==want && TTAG(d1w)==want && TTAG(d1mw)==want &&
                                      TTAG(d2w)==want && TTAG(d3w)==want && TTAG(d3pw)==want);
          if (okU && okD) break;
          __builtin_amdgcn_s_sleep(1);
          u5w = tld(up+5*256+tx);
          d0w = tld(dn+0*256+tx); d1w = tld(dn+1*256+tx); d1mw = tld(dn+1*256+txm);
          d2w = tld(dn+2*256+tx); d3w = tld(dn+3*256+tx); d3pw = tld(dn+3*256+txp);
        }
      }
    }

    // ========== A-boundary ==========
    if (ty == 0) {
      // k=0: gy = lo-1 (halo replica; valid iff hasUp)
      if (hasUp) {
        const float syy2 = TVAL(u4w), syy3 = TVAL(u5w);
        const float sxy3t = TVAL(u6w), sxy3m = TVAL(u6mw);
        const float sxx3t = TVAL(u7w), sxx3p = TVAL(u7pw);
        float d, u1, u2, u3, u4;
        d = (syy3 - syy2) * INVD;
        myy[0] = byv[0]*myy[0] + ayv[0]*d; u1 = d + myy[0];
        d = xm_ok ? (sxy3t - sxy3m) * INVD : 0.f;
        myx[0] = bxv*myx[0] + axv*d; u2 = d + myx[0];
        vy_[0] += dtb_[0]*(u1+u2);
        d = (S[1][0][tx] - sxy3t) * INVD;
        mxyy[0] = byv[0]*mxyy[0] + ayv[0]*d; u3 = d + mxyy[0];
        d = xp_ok ? (sxx3p - sxx3t) * INVD : 0.f;
        mxx[0] = bxv*mxx[0] + axv*d; u4 = d + mxx[0];
        vx_[0] += dtb_[0]*(u3+u4);
        if (sk0 == 0) vy_[0] += a0*dtb_[0];
        if (sk1 == 0) vy_[0] += a1*dtb_[0];
        V[0][0][tx] = vy_[0]; V[1][0][tx] = vx_[0];
      }
      // k=2: gy = lo+3 (own bottom row)
      {
        const float sxy4t = TVAL(d1w);
        float d, u1, u2, u3, u4;
        d = (S[0][3][tx] - S[0][2][tx]) * INVD;
        myy[2] = byv[2]*myy[2] + ayv[2]*d; u1 = d + myy[2];
        d = xm_ok ? (S[1][3][tx] - S[1][3][txm]) * INVD : 0.f;
        myx[2] = bxv*myx[2] + axv*d; u2 = d + myx[2];
        vy_[2] += dtb_[2]*(u1+u2);
        d = hasDn ? (sxy4t - S[1][3][tx]) * INVD : 0.f;
        mxyy[2] = byv[2]*mxyy[2] + ayv[2]*d; u3 = d + mxyy[2];
        d = xp_ok ? (S[2][3][txp] - S[2][3][tx]) * INVD : 0.f;
        mxx[2] = bxv*mxx[2] + axv*d; u4 = d + mxx[2];
        vx_[2] += dtb_[2]*(u3+u4);
        if (sk0 == 2) vy_[2] += a0*dtb_[2];
        if (sk1 == 2) vy_[2] += a1*dtb_[2];
        V[0][4][tx] = vy_[2]; V[1][4][tx] = vx_[2];
      }
    } else {
      // k=0: gy = lo (own top row)
      {
        const float syyU = TVAL(u5w);
        float d, u1, u2, u3, u4;
        d = hasUp ? (S[0][0][tx] - syyU) * INVD : 0.f;
        myy[0] = byv[0]*myy[0] + ayv[0]*d; u1 = d + myy[0];
        d = xm_ok ? (S[1][0][tx] - S[1][0][txm]) * INVD : 0.f;
        myx[0] = bxv*myx[0] + axv*d; u2 = d + myx[0];
        vy_[0] += dtb_[0]*(u1+u2);
        d = (S[1][1][tx] - S[1][0][tx]) * INVD;
        mxyy[0] = byv[0]*mxyy[0] + ayv[0]*d; u3 = d + mxyy[0];
        d = xp_ok ? (S[2][0][txp] - S[2][0][tx]) * INVD : 0.f;
        mxx[0] = bxv*mxx[0] + axv*d; u4 = d + mxx[0];
        vx_[0] += dtb_[0]*(u3+u4);
        if (sk0 == 0) vy_[0] += a0*dtb_[0];
        if (sk1 == 0) vy_[0] += a1*dtb_[0];
        V[0][1][tx] = vy_[0]; V[1][1][tx] = vx_[0];
      }
      // k=2: gy = lo+4 (halo replica; valid iff hasDn)
      if (hasDn) {
        const float syyD0 = TVAL(d0w), sxyD0t = TVAL(d1w), sxyD0m = TVAL(d1mw);
        const float sxyD1t = TVAL(d2w), sxxD0t = TVAL(d3w), sxxD0p = TVAL(d3pw);
        float d, u1, u2, u3, u4;
        d = (syyD0 - S[0][3][tx]) * INVD;
        myy[2] = byv[2]*myy[2] + ayv[2]*d; u1 = d + myy[2];
        d = xm_ok ? (sxyD0t - sxyD0m) * INVD : 0.f;
        myx[2] = bxv*myx[2] + axv*d; u2 = d + myx[2];
        vy_[2] += dtb_[2]*(u1+u2);
        d = (sxyD1t - sxyD0t) * INVD;
        mxyy[2] = byv[2]*mxyy[2] + ayv[2]*d; u3 = d + mxyy[2];
        d = xp_ok ? (sxxD0p - sxxD0t) * INVD : 0.f;
        mxx[2] = bxv*mxx[2] + axv*d; u4 = d + mxx[2];
        vx_[2] += dtb_[2]*(u3+u4);
        if (sk0 == 2) vy_[2] += a0*dtb_[2];
        if (sk1 == 2) vy_[2] += a1*dtb_[2];
        V[0][5][tx] = vy_[2]; V[1][5][tx] = vx_[2];
      }
    }

    bar_lds();   // all V rows visible (LDS-only wait; IF stores keep flowing)

    // ========== B: stress on own 4 rows; tag-store boundary values ASAP ==========
    unsigned long long* my = tagb + ((size_t)(t&1)*NBLK + blk)*TBLK;
    const unsigned wtag = (unsigned)(t + 1);
    #pragma unroll
    for (int j = 0; j < 2; ++j) {
      const int gy = lo + ty + 2*j;
      const int vr = ty + 2*j + 1;
      float d, u5, u6, u7, u8;
      d = (gy < NYr-1) ? (V[0][vr+1][tx] - V[0][vr][tx]) * INVD : 0.f;  // dfy(vy)
      mvyy[j] = bys[j]*mvyy[j] + ays[j]*d; u5 = d + mvyy[j];
      d = xm_ok ? (V[1][vr][tx] - V[1][vr][txm]) * INVD : 0.f;          // dbx(vx)
      mvxx[j] = bxv*mvxx[j] + axv*d; u6 = d + mvxx[j];
      syy_[j] += DTv*(l2mv[j]*u5 + lamv[j]*u6);
      sxx_[j] += DTv*(lamv[j]*u5 + l2mv[j]*u6);
      d = xm_ok ? (V[0][vr][tx] - V[0][vr][txm]) * INVD : 0.f;          // dbx(vy)
      mvyx[j] = bxv*mvyx[j] + axv*d; u7 = d + mvyx[j];
      d = (gy > 0) ? (V[1][vr][tx] - V[1][vr-1][tx]) * INVD : 0.f;      // dby(vx)
      mvxy[j] = bys[j]*mvxy[j] + ays[j]*d; u8 = d + mvxy[j];
      sxy_[j] += DTv*muv[j]*(u7 + u8);
      const int r = ty + 2*j;
      // tagged stores first (they're on the neighbor's critical path)
      if (r == 0) {
        tst(my + 0*256 + tx, syy_[j], wtag);
        tst(my + 1*256 + tx, sxy_[j], wtag);
        tst(my + 3*256 + tx, sxx_[j], wtag);
      } else if (r == 1) {
        tst(my + 2*256 + tx, sxy_[j], wtag);
      } else if (r == 2) {
        tst(my + 4*256 + tx, syy_[j], wtag);
      } else {
        tst(my + 5*256 + tx, syy_[j], wtag);
        tst(my + 6*256 + tx, sxy_[j], wtag);
        tst(my + 7*256 + tx, sxx_[j], wtag);
      }
      S[0][r][tx] = syy_[j]; S[1][r][tx] = sxy_[j]; S[2][r][tx] = sxx_[j];
    }
    bar_lds();   // S rows visible for next step's A-interior (no vmem drain)

    // ========== recording AFTER the barrier (off the critical path) ==========
    if (recA) {
      const float v = ty ? vy_[0] : vy_[1];
      unsigned long long m = mA0; while (m) { int i = __ffsll((long long)m)-1; m &= m-1; out[i*NTr + t] = v; }
      m = mA1; while (m) { int i = __ffsll((long long)m)-1; m &= m-1; out[(i+64)*NTr + t] = v; }
    }
    if (recB) {
      const float v = ty ? vy_[1] : vy_[2];
      unsigned long long m = mB0; while (m) { int i = __ffsll((long long)m)-1; m &= m-1; out[i*NTr + t] = v; }
      m = mB1; while (m) { int i = __ffsll((long long)m)-1; m &= m-1; out[(i+64)*NTr + t] = v; }
    }
  }
}

extern "C" void kernel_launch(void* const* d_in, const int* in_sizes, int n_in,
                              void* d_out, int out_size, void* d_ws, size_t ws_size,
                              hipStream_t stream) {
  const float* lamb    = (const float*)d_in[0];
  const float* mu      = (const float*)d_in[1];
  const float* buoy    = (const float*)d_in[2];
  const float* amps    = (const float*)d_in[3];
  const int*   src_loc = (const int*)d_in[4];
  const int*   rec_loc = (const int*)d_in[5];
  float* out = (float*)d_out;
  float* ws  = (float*)d_ws;

  // tag region must start at 0 every launch (tags 1..256 within one run)
  hipMemsetAsync((char*)ws + TAG_F_OFF*sizeof(float), 0,
                 (size_t)2*NBLK*TBLK*sizeof(unsigned long long), stream);

  hipLaunchKernelGGL(setup_kernel, dim3(1), dim3(256), 0, stream,
                     lamb, mu, buoy, ws + COEF_OFF);

  void* args[] = { (void*)&lamb, (void*)&mu, (void*)&buoy, (void*)&amps,
                   (void*)&src_loc, (void*)&rec_loc, (void*)&ws, (void*)&out };
  hipLaunchCooperativeKernel((void*)elastic_tag5, dim3(NBLK), dim3(512),
                             args, 0, stream);
}